// Round 1
// baseline (123.907 us; speedup 1.0000x reference)
//
#include <hip/hip_runtime.h>

#define NH      32
#define HID     128
#define E_TOT   262144
#define P_WT    4352        // global W'T row pitch (bf16 elems), padded past 4256
#define K_EXT   4256        // 133 steps * 32
#define CH_S    16          // s-steps per main chunk
#define NCHUNK  8           // 8*16 = 128 main steps
#define LDSW_P  520         // LDS W row pitch (512 + 8 pad) in bf16 elems
#define ULDS_P  20          // LDS u row pitch (16 + 4 pad) in bf16 elems

typedef float        f32x4 __attribute__((ext_vector_type(4)));
typedef short        s16x8 __attribute__((ext_vector_type(8)));
typedef unsigned int u32x4 __attribute__((ext_vector_type(4)));

static __device__ __forceinline__ short f2bf(float f) {
    __bf16 b = (__bf16)f;
    return __builtin_bit_cast(short, b);
}
static __device__ __forceinline__ float bf2f(unsigned short r) {
    unsigned int u = ((unsigned int)r) << 16;
    return __builtin_bit_cast(float, u);
}
static __device__ __forceinline__ float selu_f(float x) {
    const float kScale  = 1.0507009873554804934193349852946f;
    const float kAlphaS = 1.7580993408473768599402175208123f; // scale*alpha
    float neg = kAlphaS * (__expf(x) - 1.0f);
    return x > 0.0f ? kScale * x : neg;
}

// ---- pre-kernel: build W'T[i][kappa] (bf16), kappa layout:
//   kappa <  4096 : k=kappa>>5, j=kappa&31  -> W_A2[k][i*32+j]
//   4096..4127    : j=kappa-4096            -> b_A2[i*32+j]
//   4128..4255    : t=kappa-4128            -> W_b2[t][i]
__global__ void wt_build(const float* __restrict__ W_A2, const float* __restrict__ b_A2,
                         const float* __restrict__ W_b2, unsigned short* __restrict__ WT) {
    int gid = blockIdx.x * 256 + threadIdx.x;
    if (gid >= 32 * K_EXT) return;
    int i = gid / K_EXT;
    int kap = gid - i * K_EXT;
    float v;
    if (kap < 4096) {
        int k = kap >> 5, j = kap & 31;
        v = W_A2[k * 1024 + i * 32 + j];
    } else if (kap < 4128) {
        int j = kap - 4096;
        v = b_A2[i * 32 + j];
    } else {
        int t = kap - 4128;
        v = W_b2[t * 32 + i];
    }
    WT[i * P_WT + kap] = (unsigned short)f2bf(v);
}

typedef const __attribute__((address_space(1))) unsigned int GU32;
typedef __attribute__((address_space(3))) unsigned int LU32;
static __device__ __forceinline__ void gload_lds16(const void* g, void* l) {
    __builtin_amdgcn_global_load_lds((GU32*)g, (LU32*)l, 16, 0, 0);
}

__global__ void __launch_bounds__(256, 3)
msg_main(const float* __restrict__ h_i, const float* __restrict__ e_ij,
         const float* __restrict__ W_A1, const float* __restrict__ b_A1,
         const float* __restrict__ W_b1, const float* __restrict__ b_b1,
         const float* __restrict__ b_b2,
         const unsigned short* __restrict__ WT,
         float* __restrict__ out)
{
    __shared__ unsigned short ldsW[32 * LDSW_P];      // 33,280 B
    __shared__ unsigned short ulds[256 * ULDS_P];     // 10,240 B
    __shared__ float cA1[HID], cBA1[HID], cB1a[HID], cB1b[HID], cb2[NH];

    const int tid  = threadIdx.x;
    const int lane = tid & 63;
    const int wid  = tid >> 6;
    const int lrow = lane & 15;
    const int g    = lane >> 4;
    const int e0   = blockIdx.x * 256 + wid * 64;

    // stage small constants
    if (tid < HID) {
        cA1[tid]  = W_A1[tid];
        cBA1[tid] = b_A1[tid];
        cB1a[tid] = W_b1[tid];
        cB1b[tid] = b_b1[tid];
    }
    if (tid < NH) cb2[tid] = b_b2[tid];

    // per-thread edge scalar for u-fill (thread t owns local edge t)
    const float ev_fill = e_ij[blockIdx.x * 256 + tid];

    // persistent h fragments (f32) + per-M-tile edge scalars
    f32x4 hf[4][2];
    float evm[4];
    #pragma unroll
    for (int mt = 0; mt < 4; ++mt) {
        int er = e0 + mt * 16 + lrow;
        const float* hp = h_i + er * 32 + g * 8;
        hf[mt][0] = *(const f32x4*)hp;
        hf[mt][1] = *(const f32x4*)(hp + 4);
        evm[mt] = e_ij[er];
    }

    f32x4 acc[4][2];
    #pragma unroll
    for (int mt = 0; mt < 4; ++mt)
        #pragma unroll
        for (int nt = 0; nt < 2; ++nt)
            acc[mt][nt] = (f32x4){0.f, 0.f, 0.f, 0.f};

    __syncthreads();   // consts visible before first u-fill

    const unsigned short* uw = ulds + (wid * 64 + lrow) * ULDS_P;

    for (int c = 0; c < NCHUNK; ++c) {
        const int kap0 = c * CH_S * 32;   // 512*c

        // ---- stage W chunk: wave wid stages rows [wid*8, wid*8+8), 1024 B each
        #pragma unroll
        for (int r = 0; r < 8; ++r) {
            int i = wid * 8 + r;
            const unsigned short* src = WT + i * P_WT + kap0 + lane * 8;
            gload_lds16(src, &ldsW[i * LDSW_P]);
        }

        // ---- u-fill for this chunk (wave-local rows)
        {
            unsigned short* urow = ulds + tid * ULDS_P;
            #pragma unroll
            for (int sl = 0; sl < CH_S; sl += 2) {
                int s = c * CH_S + sl;
                float u0 = selu_f(fmaf(ev_fill, cA1[s],     cBA1[s]));
                float u1 = selu_f(fmaf(ev_fill, cA1[s + 1], cBA1[s + 1]));
                unsigned int pk = (unsigned int)(unsigned short)f2bf(u0)
                                | ((unsigned int)(unsigned short)f2bf(u1) << 16);
                *(unsigned int*)(urow + sl) = pk;
            }
        }
        __syncthreads();   // drains vmcnt (global_load_lds) + lgkm

        // ---- compute 16 K-steps
        #pragma unroll
        for (int sl = 0; sl < CH_S; ++sl) {
            u32x4 r0 = *(const u32x4*)&ldsW[lrow        * LDSW_P + sl * 32 + g * 8];
            u32x4 r1 = *(const u32x4*)&ldsW[(lrow + 16) * LDSW_P + sl * 32 + g * 8];
            s16x8 B0 = __builtin_bit_cast(s16x8, r0);
            s16x8 B1 = __builtin_bit_cast(s16x8, r1);
            #pragma unroll
            for (int mt = 0; mt < 4; ++mt) {
                float us = bf2f(uw[mt * 16 * ULDS_P + sl]);
                s16x8 A;
                #pragma unroll
                for (int p = 0; p < 4; ++p) {
                    A[p]     = f2bf(us * hf[mt][0][p]);
                    A[p + 4] = f2bf(us * hf[mt][1][p]);
                }
                acc[mt][0] = __builtin_amdgcn_mfma_f32_16x16x32_bf16(A, B0, acc[mt][0], 0, 0, 0);
                acc[mt][1] = __builtin_amdgcn_mfma_f32_16x16x32_bf16(A, B1, acc[mt][1], 0, 0, 0);
            }
        }
        __syncthreads();   // before overwriting ldsW / ulds
    }

    // ---- tail: kappa 4096..4255 (5 steps: b_A2 row + 4 b-path steps)
    {
        int i   = tid >> 3;          // 0..31
        int seg = tid & 7;           // 8 segs * 20 elems = 160
        const unsigned short* src = WT + i * P_WT + 4096 + seg * 20;
        unsigned short* dst = ldsW + i * LDSW_P + seg * 20;
        #pragma unroll
        for (int q = 0; q < 20; ++q) dst[q] = src[q];
    }
    __syncthreads();

    // step 128: A = h (u == 1), B = b_A2 columns
    {
        u32x4 r0 = *(const u32x4*)&ldsW[lrow        * LDSW_P + g * 8];
        u32x4 r1 = *(const u32x4*)&ldsW[(lrow + 16) * LDSW_P + g * 8];
        s16x8 B0 = __builtin_bit_cast(s16x8, r0);
        s16x8 B1 = __builtin_bit_cast(s16x8, r1);
        #pragma unroll
        for (int mt = 0; mt < 4; ++mt) {
            s16x8 A;
            #pragma unroll
            for (int p = 0; p < 4; ++p) {
                A[p]     = f2bf(hf[mt][0][p]);
                A[p + 4] = f2bf(hf[mt][1][p]);
            }
            acc[mt][0] = __builtin_amdgcn_mfma_f32_16x16x32_bf16(A, B0, acc[mt][0], 0, 0, 0);
            acc[mt][1] = __builtin_amdgcn_mfma_f32_16x16x32_bf16(A, B1, acc[mt][1], 0, 0, 0);
        }
    }

    // steps 129..132: A[e, j] = selu(e_val*W_b1[32q+j] + b_b1[...]), B = W_b2
    #pragma unroll
    for (int q = 0; q < 4; ++q) {
        int tb = q * 32 + g * 8;
        f32x4 wb0 = *(const f32x4*)&cB1a[tb];
        f32x4 wb1 = *(const f32x4*)&cB1a[tb + 4];
        f32x4 bb0 = *(const f32x4*)&cB1b[tb];
        f32x4 bb1 = *(const f32x4*)&cB1b[tb + 4];
        u32x4 r0 = *(const u32x4*)&ldsW[lrow        * LDSW_P + (1 + q) * 32 + g * 8];
        u32x4 r1 = *(const u32x4*)&ldsW[(lrow + 16) * LDSW_P + (1 + q) * 32 + g * 8];
        s16x8 B0 = __builtin_bit_cast(s16x8, r0);
        s16x8 B1 = __builtin_bit_cast(s16x8, r1);
        #pragma unroll
        for (int mt = 0; mt < 4; ++mt) {
            s16x8 A;
            #pragma unroll
            for (int p = 0; p < 4; ++p) {
                A[p]     = f2bf(selu_f(fmaf(evm[mt], wb0[p], bb0[p])));
                A[p + 4] = f2bf(selu_f(fmaf(evm[mt], wb1[p], bb1[p])));
            }
            acc[mt][0] = __builtin_amdgcn_mfma_f32_16x16x32_bf16(A, B0, acc[mt][0], 0, 0, 0);
            acc[mt][1] = __builtin_amdgcn_mfma_f32_16x16x32_bf16(A, B1, acc[mt][1], 0, 0, 0);
        }
    }

    // ---- epilogue: add b_b2, store. C/D: col = lane&15, row = g*4 + reg
    float bbv[2] = { cb2[lrow], cb2[lrow + 16] };
    #pragma unroll
    for (int mt = 0; mt < 4; ++mt) {
        #pragma unroll
        for (int nt = 0; nt < 2; ++nt) {
            #pragma unroll
            for (int r = 0; r < 4; ++r) {
                int edge = e0 + mt * 16 + g * 4 + r;
                out[edge * 32 + nt * 16 + lrow] = acc[mt][nt][r] + bbv[nt];
            }
        }
    }
}

extern "C" void kernel_launch(void* const* d_in, const int* in_sizes, int n_in,
                              void* d_out, int out_size, void* d_ws, size_t ws_size,
                              hipStream_t stream) {
    const float* h_i  = (const float*)d_in[0];
    const float* e_ij = (const float*)d_in[1];
    const float* W_A1 = (const float*)d_in[2];
    const float* b_A1 = (const float*)d_in[3];
    const float* W_A2 = (const float*)d_in[4];
    const float* b_A2 = (const float*)d_in[5];
    const float* W_b1 = (const float*)d_in[6];
    const float* b_b1 = (const float*)d_in[7];
    const float* W_b2 = (const float*)d_in[8];
    const float* b_b2 = (const float*)d_in[9];

    unsigned short* WT = (unsigned short*)d_ws;   // 32 * P_WT * 2 = 278,528 B

    wt_build<<<(32 * K_EXT + 255) / 256, 256, 0, stream>>>(W_A2, b_A2, W_b2, WT);
    msg_main<<<E_TOT / 256, 256, 0, stream>>>(h_i, e_ij, W_A1, b_A1, W_b1, b_b1,
                                              b_b2, WT, (float*)d_out);
}

// Round 2
// 100.976 us; speedup vs baseline: 1.2271x; 1.2271x over previous
//
#include <hip/hip_runtime.h>

#define NH      32
#define HID     128
#define E_TOT   262144
#define P_WT    4352        // global W'T row pitch (bf16 elems), padded past 4256
#define K_EXT   4256        // 133 steps * 32
#define CH_S    16          // s-steps per main chunk
#define NCHUNK  8           // 8*16 = 128 main steps
#define LDSW_P  520         // LDS W row pitch (512 + 8 pad) in bf16 elems

typedef float        f32x4 __attribute__((ext_vector_type(4)));
typedef short        s16x8 __attribute__((ext_vector_type(8)));
typedef unsigned int u32x4 __attribute__((ext_vector_type(4)));

static __device__ __forceinline__ short f2bf(float f) {
    __bf16 b = (__bf16)f;
    return __builtin_bit_cast(short, b);
}
static __device__ __forceinline__ float selu_f(float x) {
    const float kScale  = 1.0507009873554804934193349852946f;
    const float kAlphaS = 1.7580993408473768599402175208123f; // scale*alpha
    float neg = kAlphaS * (__expf(x) - 1.0f);
    return x > 0.0f ? kScale * x : neg;
}

// ---- pre-kernel: build W'T[i][kappa] (bf16), kappa layout:
//   kappa <  4096 : k=kappa>>5, j=kappa&31  -> W_A2[k][i*32+j]
//   4096..4127    : j=kappa-4096            -> b_A2[i*32+j]
//   4128..4255    : t=kappa-4128            -> W_b2[t][i]
__global__ void wt_build(const float* __restrict__ W_A2, const float* __restrict__ b_A2,
                         const float* __restrict__ W_b2, unsigned short* __restrict__ WT) {
    int gid = blockIdx.x * 256 + threadIdx.x;
    if (gid >= 32 * K_EXT) return;
    int i = gid / K_EXT;
    int kap = gid - i * K_EXT;
    float v;
    if (kap < 4096) {
        int k = kap >> 5, j = kap & 31;
        v = W_A2[k * 1024 + i * 32 + j];
    } else if (kap < 4128) {
        int j = kap - 4096;
        v = b_A2[i * 32 + j];
    } else {
        int t = kap - 4128;
        v = W_b2[t * 32 + i];
    }
    WT[i * P_WT + kap] = (unsigned short)f2bf(v);
}

typedef const __attribute__((address_space(1))) unsigned int GU32;
typedef __attribute__((address_space(3))) unsigned int LU32;
static __device__ __forceinline__ void gload_lds16(const void* g, void* l) {
    __builtin_amdgcn_global_load_lds((GU32*)g, (LU32*)l, 16, 0, 0);
}

// Transposed orientation: D[i_local, e_local] per (itile, col-tile).
//   A (MFMA rows)   = W'T slice  : lane row  = lane&15 -> i_local, k = g*8+p  (LDS b128)
//   B (MFMA cols)   = h fragment : lane col  = lane&15 -> e_local, k = g*8+p  (regs, bf16 once)
//   per step: tmp = A*B; acc += u_s[e] * tmp   (u scalar per lane per col-tile)
__global__ void __launch_bounds__(256, 3)
msg_main(const float* __restrict__ h_i, const float* __restrict__ e_ij,
         const float* __restrict__ W_A1, const float* __restrict__ b_A1,
         const float* __restrict__ W_b1, const float* __restrict__ b_b1,
         const float* __restrict__ b_b2,
         const unsigned short* __restrict__ WT,
         float* __restrict__ out)
{
    __shared__ unsigned short ldsW[32 * LDSW_P];      // 33,280 B
    __shared__ float ut[CH_S][256];                   // 16,384 B  u_t[s][edge_local]
    __shared__ float cA1[HID], cBA1[HID], cB1a[HID], cB1b[HID], cb2[NH];

    const int tid  = threadIdx.x;
    const int lane = tid & 63;
    const int wid  = tid >> 6;
    const int lrow = lane & 15;
    const int g    = lane >> 4;
    const int e0   = blockIdx.x * 256 + wid * 64;
    const int wbase = wid * 64;

    // stage small constants
    if (tid < HID) {
        cA1[tid]  = W_A1[tid];
        cBA1[tid] = b_A1[tid];
        cB1a[tid] = W_b1[tid];
        cB1b[tid] = b_b1[tid];
    }
    if (tid < NH) cb2[tid] = b_b2[tid];

    // per-thread edge scalar for u-fill (thread t owns local edge t)
    const float ev_fill = e_ij[blockIdx.x * 256 + tid];

    // persistent bf16 h fragments (B operand) + per-col-tile edge scalars (tail)
    s16x8 hb[4];
    float ev[4];
    #pragma unroll
    for (int ct = 0; ct < 4; ++ct) {
        int er = e0 + ct * 16 + lrow;
        const float* hp = h_i + er * 32 + g * 8;
        f32x4 h0 = *(const f32x4*)hp;
        f32x4 h1 = *(const f32x4*)(hp + 4);
        #pragma unroll
        for (int p = 0; p < 4; ++p) {
            hb[ct][p]     = f2bf(h0[p]);
            hb[ct][p + 4] = f2bf(h1[p]);
        }
        ev[ct] = e_ij[er];
    }

    f32x4 acc[4][2];
    #pragma unroll
    for (int ct = 0; ct < 4; ++ct)
        #pragma unroll
        for (int it = 0; it < 2; ++it)
            acc[ct][it] = (f32x4){0.f, 0.f, 0.f, 0.f};
    const f32x4 zf = (f32x4){0.f, 0.f, 0.f, 0.f};

    __syncthreads();   // consts visible before first u-fill

    for (int c = 0; c < NCHUNK; ++c) {
        const int kap0 = c * CH_S * 32;   // 512*c

        // ---- stage W chunk: wave wid stages rows [wid*8, wid*8+8), 1024 B each
        #pragma unroll
        for (int r = 0; r < 8; ++r) {
            int i = wid * 8 + r;
            const unsigned short* src = WT + i * P_WT + kap0 + lane * 8;
            gload_lds16(src, &ldsW[i * LDSW_P]);
        }

        // ---- u-fill: thread t computes u for its edge, 16 s-values
        #pragma unroll
        for (int sl = 0; sl < CH_S; ++sl) {
            int s = c * CH_S + sl;
            ut[sl][tid] = selu_f(fmaf(ev_fill, cA1[s], cBA1[s]));
        }
        __syncthreads();   // drains vmcnt (global_load_lds) + lgkm

        // ---- compute 16 K-steps
        #pragma unroll
        for (int sl = 0; sl < CH_S; ++sl) {
            u32x4 r0 = *(const u32x4*)&ldsW[lrow        * LDSW_P + sl * 32 + g * 8];
            u32x4 r1 = *(const u32x4*)&ldsW[(lrow + 16) * LDSW_P + sl * 32 + g * 8];
            s16x8 A0 = __builtin_bit_cast(s16x8, r0);
            s16x8 A1 = __builtin_bit_cast(s16x8, r1);
            const float* urow = &ut[sl][wbase];
            #pragma unroll
            for (int ct = 0; ct < 4; ++ct) {
                float uv = urow[ct * 16 + lrow];
                f32x4 t0 = __builtin_amdgcn_mfma_f32_16x16x32_bf16(A0, hb[ct], zf, 0, 0, 0);
                f32x4 t1 = __builtin_amdgcn_mfma_f32_16x16x32_bf16(A1, hb[ct], zf, 0, 0, 0);
                f32x4 u4 = (f32x4){uv, uv, uv, uv};
                acc[ct][0] = __builtin_elementwise_fma(t0, u4, acc[ct][0]);
                acc[ct][1] = __builtin_elementwise_fma(t1, u4, acc[ct][1]);
            }
        }
        __syncthreads();   // before overwriting ldsW / ut
    }

    // ---- tail: kappa 4096..4255 (5 steps: b_A2 row + 4 b-path steps)
    {
        int i   = tid >> 3;          // 0..31
        int seg = tid & 7;           // 8 segs * 20 elems = 160
        const unsigned short* src = WT + i * P_WT + 4096 + seg * 20;
        unsigned short* dst = ldsW + i * LDSW_P + seg * 20;
        #pragma unroll
        for (int q = 0; q < 20; ++q) dst[q] = src[q];
    }
    __syncthreads();

    // step 128: pseudo-u == 1, A = b_A2 columns, B = h  -> accumulate directly
    {
        u32x4 r0 = *(const u32x4*)&ldsW[lrow        * LDSW_P + g * 8];
        u32x4 r1 = *(const u32x4*)&ldsW[(lrow + 16) * LDSW_P + g * 8];
        s16x8 A0 = __builtin_bit_cast(s16x8, r0);
        s16x8 A1 = __builtin_bit_cast(s16x8, r1);
        #pragma unroll
        for (int ct = 0; ct < 4; ++ct) {
            acc[ct][0] = __builtin_amdgcn_mfma_f32_16x16x32_bf16(A0, hb[ct], acc[ct][0], 0, 0, 0);
            acc[ct][1] = __builtin_amdgcn_mfma_f32_16x16x32_bf16(A1, hb[ct], acc[ct][1], 0, 0, 0);
        }
    }

    // steps 129..132: A = W_b2 columns, B[j,e] = selu(e_e*W_b1[32q+j] + b_b1[...])
    #pragma unroll
    for (int q = 0; q < 4; ++q) {
        int tb = q * 32 + g * 8;
        f32x4 wb0 = *(const f32x4*)&cB1a[tb];
        f32x4 wb1 = *(const f32x4*)&cB1a[tb + 4];
        f32x4 bb0 = *(const f32x4*)&cB1b[tb];
        f32x4 bb1 = *(const f32x4*)&cB1b[tb + 4];
        u32x4 r0 = *(const u32x4*)&ldsW[lrow        * LDSW_P + (1 + q) * 32 + g * 8];
        u32x4 r1 = *(const u32x4*)&ldsW[(lrow + 16) * LDSW_P + (1 + q) * 32 + g * 8];
        s16x8 A0 = __builtin_bit_cast(s16x8, r0);
        s16x8 A1 = __builtin_bit_cast(s16x8, r1);
        #pragma unroll
        for (int ct = 0; ct < 4; ++ct) {
            s16x8 B;
            #pragma unroll
            for (int p = 0; p < 4; ++p) {
                B[p]     = f2bf(selu_f(fmaf(ev[ct], wb0[p], bb0[p])));
                B[p + 4] = f2bf(selu_f(fmaf(ev[ct], wb1[p], bb1[p])));
            }
            acc[ct][0] = __builtin_amdgcn_mfma_f32_16x16x32_bf16(A0, B, acc[ct][0], 0, 0, 0);
            acc[ct][1] = __builtin_amdgcn_mfma_f32_16x16x32_bf16(A1, B, acc[ct][1], 0, 0, 0);
        }
    }

    // ---- epilogue: add b_b2, store. C/D: col = lane&15 -> e_local, row = g*4+r -> i_local
    #pragma unroll
    for (int it = 0; it < 2; ++it) {
        f32x4 b2v = *(const f32x4*)&cb2[it * 16 + g * 4];
        #pragma unroll
        for (int ct = 0; ct < 4; ++ct) {
            int edge = e0 + ct * 16 + lrow;
            f32x4 vo = acc[ct][it] + b2v;
            *(f32x4*)&out[edge * 32 + it * 16 + g * 4] = vo;
        }
    }
}

extern "C" void kernel_launch(void* const* d_in, const int* in_sizes, int n_in,
                              void* d_out, int out_size, void* d_ws, size_t ws_size,
                              hipStream_t stream) {
    const float* h_i  = (const float*)d_in[0];
    const float* e_ij = (const float*)d_in[1];
    const float* W_A1 = (const float*)d_in[2];
    const float* b_A1 = (const float*)d_in[3];
    const float* W_A2 = (const float*)d_in[4];
    const float* b_A2 = (const float*)d_in[5];
    const float* W_b1 = (const float*)d_in[6];
    const float* b_b1 = (const float*)d_in[7];
    const float* W_b2 = (const float*)d_in[8];
    const float* b_b2 = (const float*)d_in[9];

    unsigned short* WT = (unsigned short*)d_ws;   // 32 * P_WT * 2 = 278,528 B

    wt_build<<<(32 * K_EXT + 255) / 256, 256, 0, stream>>>(W_A2, b_A2, W_b2, WT);
    msg_main<<<E_TOT / 256, 256, 0, stream>>>(h_i, e_ij, W_A1, b_A1, W_b1, b_b1,
                                              b_b2, WT, (float*)d_out);
}